// Round 3
// baseline (5414.706 us; speedup 1.0000x reference)
//
#include <hip/hip_runtime.h>

typedef _Float16 half2_t __attribute__((ext_vector_type(2)));
typedef _Float16 half8_t __attribute__((ext_vector_type(8)));
typedef float floatx4 __attribute__((ext_vector_type(4)));
typedef unsigned int u32;

#define BB 64
#define TT 2048
#define II 128
#define HH 256
#define CC 64
#define G3 (3*HH)          // 768
#define MTOT (BB*TT)       // 131072

static __device__ __forceinline__ float fast_rcp(float x) {
    return __builtin_amdgcn_rcpf(x);
}

// ---------------------------------------------------------------------------
// MFMA GEMM: C[M,N] = A[M,K] @ W[N,K]^T + bias.  (validated in round 1)
// ---------------------------------------------------------------------------
template<typename AT, typename CT>
__global__ __launch_bounds__(256, 2)
void gemm_mfma(const AT* __restrict__ A, const float* __restrict__ W,
               const float* __restrict__ bias, CT* __restrict__ Cout,
               int M, int N, int K)
{
    __shared__ alignas(16) u32 As32[128 * 32];   // [row][8 slots of 16B], swizzled
    __shared__ alignas(16) u32 Bs32[64 * 32];

    const int tid  = threadIdx.x;
    const int lane = tid & 63;
    const int wave = tid >> 6;        // 0..3
    const int wm   = wave >> 1;       // 0..1 -> m offset 64*wm
    const int wn   = wave & 1;        // 0..1 -> n offset 32*wn
    const int m0   = blockIdx.y * 128;
    const int n0   = blockIdx.x * 64;
    const int lr   = lane & 15;       // fragment row/col
    const int lg   = lane >> 4;       // k-group 0..3

    floatx4 acc[4][2] = {};

    for (int kc = 0; kc < K; kc += 64) {
        // ---- stage A: 128 rows x 64 f16 = 1024 x 16B slots, 4 iters ----
        #pragma unroll
        for (int it = 0; it < 4; ++it) {
            const int s    = it * 256 + tid;
            const int row  = s >> 3;          // 0..127
            const int slot = s & 7;           // 0..7 (8 f16 each)
            const AT* src  = A + (size_t)(m0 + row) * K + kc + slot * 8;
            half8_t v;
            if constexpr (sizeof(AT) == 2) {
                v = *reinterpret_cast<const half8_t*>(src);
            } else {
                const float4* s4 = reinterpret_cast<const float4*>(src);
                float4 lo = s4[0], hi = s4[1];
                v[0] = (_Float16)lo.x; v[1] = (_Float16)lo.y;
                v[2] = (_Float16)lo.z; v[3] = (_Float16)lo.w;
                v[4] = (_Float16)hi.x; v[5] = (_Float16)hi.y;
                v[6] = (_Float16)hi.z; v[7] = (_Float16)hi.w;
            }
            const int sw = slot ^ (row & 7);
            *reinterpret_cast<half8_t*>(&As32[row * 32 + sw * 4]) = v;
        }
        // ---- stage B: 64 rows x 64 f16 = 512 slots, 2 iters (fp32 W) ----
        #pragma unroll
        for (int it = 0; it < 2; ++it) {
            const int s    = it * 256 + tid;
            const int row  = s >> 3;          // 0..63
            const int slot = s & 7;
            const float* src = W + (size_t)(n0 + row) * K + kc + slot * 8;
            const float4* s4 = reinterpret_cast<const float4*>(src);
            float4 lo = s4[0], hi = s4[1];
            half8_t v;
            v[0] = (_Float16)lo.x; v[1] = (_Float16)lo.y;
            v[2] = (_Float16)lo.z; v[3] = (_Float16)lo.w;
            v[4] = (_Float16)hi.x; v[5] = (_Float16)hi.y;
            v[6] = (_Float16)hi.z; v[7] = (_Float16)hi.w;
            const int sw = slot ^ (row & 7);
            *reinterpret_cast<half8_t*>(&Bs32[row * 32 + sw * 4]) = v;
        }
        __syncthreads();

        #pragma unroll
        for (int ks = 0; ks < 2; ++ks) {
            half8_t af[4], bf[2];
            #pragma unroll
            for (int fm = 0; fm < 4; ++fm) {
                const int row  = wm * 64 + fm * 16 + lr;
                const int slot = ks * 4 + lg;
                const int sw   = slot ^ (row & 7);
                af[fm] = *reinterpret_cast<const half8_t*>(&As32[row * 32 + sw * 4]);
            }
            #pragma unroll
            for (int fn = 0; fn < 2; ++fn) {
                const int row  = wn * 32 + fn * 16 + lr;
                const int slot = ks * 4 + lg;
                const int sw   = slot ^ (row & 7);
                bf[fn] = *reinterpret_cast<const half8_t*>(&Bs32[row * 32 + sw * 4]);
            }
            #pragma unroll
            for (int fm = 0; fm < 4; ++fm)
                #pragma unroll
                for (int fn = 0; fn < 2; ++fn)
                    acc[fm][fn] = __builtin_amdgcn_mfma_f32_16x16x32_f16(
                        af[fm], bf[fn], acc[fm][fn], 0, 0, 0);
        }
        __syncthreads();
    }

    // ---- epilogue: D[row=(lane>>4)*4+reg][col=lane&15] + bias ----
    #pragma unroll
    for (int fn = 0; fn < 2; ++fn) {
        const int n = n0 + wn * 32 + fn * 16 + lr;
        const float bv = bias[n];
        #pragma unroll
        for (int fm = 0; fm < 4; ++fm) {
            #pragma unroll
            for (int r = 0; r < 4; ++r) {
                const int m = m0 + wm * 64 + fm * 16 + lg * 4 + r;
                Cout[(size_t)m * N + n] = (CT)(acc[fm][fn][r] + bv);
            }
        }
    }
}

// ---------------------------------------------------------------------------
// Persistent GRU scan, v3: MFMA matvec.  One WG per batch (64 WGs x 512 thr,
// 8 waves, 2 waves/SIMD -> 256-reg budget).
//
// Wave w owns gate-triple columns j in [32w, 32w+32):
//   r-tiles {2w,2w+1}, z-tiles {16+2w,16+2w+1}, n-tiles {32+2w,32+2w+1}.
// Weights Whh (f16-converted) live in 48 half8 fragments = 192 regs/lane,
// readable by MFMA directly from AGPRs (no accvgpr_read tax, unlike v1/v2's
// v_dot2 path).  B-frag layout = round-1-GEMM-validated: lane holds
// B[col=lane&15][k=(lane>>4)*8+e] for each k-frag.
//
// A-operand (h) via broadcast: all 16 lanes of k-group q read the SAME 16B
// h-slice from LDS (conflict-free broadcast) -> every MFMA row is a copy of
// the one real batch row; acc row 0 (lanes 0-15, elem 0) is the result.
// 8 ds_read_b128 per wave per step total; h is 512B double-buffered, ONE
// __syncthreads per step.
//
// Gate math on lanes 0-15 in-register (acc[g*2+p][0] = the (j,256+j,512+j)
// triple), gx prefetched one step ahead (3 loads + imm offsets), h_prev in
// regs. exp/rcp fast paths (validated numerics from v2).
// ---------------------------------------------------------------------------
__global__ __launch_bounds__(512, 2)
void gru_scan(const _Float16* __restrict__ gx,   // [B, T, 768] incl. b_ih
              const float* __restrict__ Whh,     // [768, 256]
              const float* __restrict__ bhh,     // [768]
              _Float16* __restrict__ hout)       // [B, T, 256]
{
    const int b    = blockIdx.x;
    const int tid  = threadIdx.x;
    const int wv   = tid >> 6;        // wave 0..7
    const int lane = tid & 63;
    const int lr   = lane & 15;       // fragment row/col
    const int lg   = lane >> 4;       // k-group 0..3

    // ---- load weight fragments: (g,p) x kf, 48 x half8 = 192 regs ----
    half8_t wf[48];
    #pragma unroll
    for (int g = 0; g < 3; ++g) {
        #pragma unroll
        for (int p = 0; p < 2; ++p) {
            const int row = g * 256 + wv * 32 + p * 16 + lr;
            #pragma unroll
            for (int kf = 0; kf < 8; ++kf) {
                const float* src = Whh + (size_t)row * HH + kf * 32 + lg * 8;
                const float4 lo = reinterpret_cast<const float4*>(src)[0];
                const float4 hi = reinterpret_cast<const float4*>(src)[1];
                half8_t v;
                v[0] = (_Float16)lo.x; v[1] = (_Float16)lo.y;
                v[2] = (_Float16)lo.z; v[3] = (_Float16)lo.w;
                v[4] = (_Float16)hi.x; v[5] = (_Float16)hi.y;
                v[6] = (_Float16)hi.z; v[7] = (_Float16)hi.w;
                wf[(g * 2 + p) * 8 + kf] = v;
            }
        }
    }

    const int j0 = wv * 32 + lr;      // j for p=0 (meaningful on lanes 0-15)
    float bhr[2], bhz[2], bhn[2];
    #pragma unroll
    for (int p = 0; p < 2; ++p) {
        bhr[p] = bhh[j0 + p * 16];
        bhz[p] = bhh[HH + j0 + p * 16];
        bhn[p] = bhh[2 * HH + j0 + p * 16];
    }

    __shared__ alignas(16) _Float16 Hs[2][HH];   // double-buffered h (2x512B)
    reinterpret_cast<_Float16*>(Hs)[tid] = (_Float16)0.f;  // zero both buffers

    const _Float16* gp = gx + (size_t)b * TT * G3 + j0;
    _Float16* op = hout + (size_t)b * TT * HH + j0;

    _Float16 pxr0 = 0, pxz0 = 0, pxn0 = 0, pxr1 = 0, pxz1 = 0, pxn1 = 0;
    if (lane < 16) {                  // prefetch step-0 input gates
        pxr0 = gp[0];       pxr1 = gp[16];
        pxz0 = gp[HH];      pxz1 = gp[HH + 16];
        pxn0 = gp[2 * HH];  pxn1 = gp[2 * HH + 16];
    }
    float hp0 = 0.f, hp1 = 0.f;       // h_prev for (p=0, p=1)
    __syncthreads();

    for (int t = 0; t < TT; ++t) {
        const _Float16* hcur = Hs[t & 1];
        _Float16*       hnxt = Hs[(t + 1) & 1];

        floatx4 acc[6] = {};
        #pragma unroll
        for (int kf = 0; kf < 8; ++kf) {
            // broadcast read: 16 lanes of group lg share one 16B h-slice
            const half8_t a = *reinterpret_cast<const half8_t*>(&hcur[kf * 32 + lg * 8]);
            #pragma unroll
            for (int i = 0; i < 6; ++i)
                acc[i] = __builtin_amdgcn_mfma_f32_16x16x32_f16(
                    a, wf[i * 8 + kf], acc[i], 0, 0, 0);
        }

        if (lane < 16) {
            // prefetch next step's gx first (full step to cover latency)
            const _Float16 nxr0 = gp[G3],           nxr1 = gp[G3 + 16];
            const _Float16 nxz0 = gp[G3 + HH],      nxz1 = gp[G3 + HH + 16];
            const _Float16 nxn0 = gp[G3 + 2 * HH],  nxn1 = gp[G3 + 2 * HH + 16];

            // ---- p = 0 ----
            {
                const float ar = acc[0][0], az = acc[2][0], an = acc[4][0];
                const float r = fast_rcp(1.f + __expf(-((float)pxr0 + ar + bhr[0])));
                const float z = fast_rcp(1.f + __expf(-((float)pxz0 + az + bhz[0])));
                const float e = __expf(2.f * ((float)pxn0 + r * (an + bhn[0])));
                const float n = 1.f - 2.f * fast_rcp(e + 1.f);
                const float hnew = (1.f - z) * n + z * hp0;
                hp0 = hnew;
                const _Float16 hf = (_Float16)hnew;
                hnxt[j0] = hf;
                op[0] = hf;
            }
            // ---- p = 1 ----
            {
                const float ar = acc[1][0], az = acc[3][0], an = acc[5][0];
                const float r = fast_rcp(1.f + __expf(-((float)pxr1 + ar + bhr[1])));
                const float z = fast_rcp(1.f + __expf(-((float)pxz1 + az + bhz[1])));
                const float e = __expf(2.f * ((float)pxn1 + r * (an + bhn[1])));
                const float n = 1.f - 2.f * fast_rcp(e + 1.f);
                const float hnew = (1.f - z) * n + z * hp1;
                hp1 = hnew;
                const _Float16 hf = (_Float16)hnew;
                hnxt[j0 + 16] = hf;
                op[16] = hf;
            }
            pxr0 = nxr0; pxz0 = nxz0; pxn0 = nxn0;
            pxr1 = nxr1; pxz1 = nxz1; pxn1 = nxn1;
        }
        __syncthreads();
        gp += G3; op += HH;
    }
}

// ---------------------------------------------------------------------------
extern "C" void kernel_launch(void* const* d_in, const int* in_sizes, int n_in,
                              void* d_out, int out_size, void* d_ws, size_t ws_size,
                              hipStream_t stream) {
    const float* x    = (const float*)d_in[0];
    const float* Wih0 = (const float*)d_in[1];
    const float* Whh0 = (const float*)d_in[2];
    const float* bih0 = (const float*)d_in[3];
    const float* bhh0 = (const float*)d_in[4];
    const float* Wih1 = (const float*)d_in[5];
    const float* Whh1 = (const float*)d_in[6];
    const float* bih1 = (const float*)d_in[7];
    const float* bhh1 = (const float*)d_in[8];
    const float* fcw  = (const float*)d_in[9];
    const float* fcb  = (const float*)d_in[10];
    float* out = (float*)d_out;

    // workspace: gx buffer (201 MB, reused for both layers) + h buffer (64 MB)
    _Float16* gxbuf = (_Float16*)d_ws;
    _Float16* hbuf  = (_Float16*)((char*)d_ws + (size_t)MTOT * G3 * sizeof(_Float16));

    const dim3 blk(256);
    // 1) gx0 = x @ W_ih0^T + b_ih0
    gemm_mfma<float, _Float16><<<dim3(G3/64, MTOT/128), blk, 0, stream>>>(
        x, Wih0, bih0, gxbuf, MTOT, G3, II);
    // 2) scan layer 0 -> h0
    gru_scan<<<dim3(BB), dim3(512), 0, stream>>>(gxbuf, Whh0, bhh0, hbuf);
    // 3) gx1 = h0 @ W_ih1^T + b_ih1 (overwrites gx buffer)
    gemm_mfma<_Float16, _Float16><<<dim3(G3/64, MTOT/128), blk, 0, stream>>>(
        hbuf, Wih1, bih1, gxbuf, MTOT, G3, HH);
    // 4) scan layer 1 -> h1 (overwrites h buffer)
    gru_scan<<<dim3(BB), dim3(512), 0, stream>>>(gxbuf, Whh1, bhh1, hbuf);
    // 5) out = h1 @ fc_w^T + fc_b
    gemm_mfma<_Float16, float><<<dim3(CC/64, MTOT/128), blk, 0, stream>>>(
        hbuf, fcw, fcb, out, MTOT, CC, HH);
}

// Round 4
// 4596.989 us; speedup vs baseline: 1.1779x; 1.1779x over previous
//
#include <hip/hip_runtime.h>

typedef _Float16 half2_t __attribute__((ext_vector_type(2)));
typedef _Float16 half8_t __attribute__((ext_vector_type(8)));
typedef float floatx4 __attribute__((ext_vector_type(4)));
typedef unsigned int u32;

#define BB 64
#define TT 2048
#define II 128
#define HH 256
#define CC 64
#define G3 (3*HH)          // 768
#define MTOT (BB*TT)       // 131072

static __device__ __forceinline__ float dot2f(half2_t a, half2_t b, float c) {
#if __has_builtin(__builtin_amdgcn_fdot2)
    return __builtin_amdgcn_fdot2(a, b, c, false);
#else
    return c + (float)a[0]*(float)b[0] + (float)a[1]*(float)b[1];
#endif
}

static __device__ __forceinline__ half2_t bch2(u32 x) {
    return __builtin_bit_cast(half2_t, x);
}

static __device__ __forceinline__ float fast_rcp(float x) {
    return __builtin_amdgcn_rcpf(x);
}

// DPP quad_perm helpers (pure VALU cross-lane, no LDS pipe).
// 0xB1 = [1,0,3,2] (xor 1), 0x4E = [2,3,0,1] (xor 2).
static __device__ __forceinline__ float pair_sum(float x) {   // lanes t,t^1 both get sum
    int i = __builtin_bit_cast(int, x);
    int a = __builtin_amdgcn_mov_dpp(i, 0xB1, 0xF, 0xF, true);
    return x + __builtin_bit_cast(float, a);
}
static __device__ __forceinline__ float dpp_xor2(float x) {   // value from lane t^2
    int i = __builtin_bit_cast(int, x);
    int a = __builtin_amdgcn_mov_dpp(i, 0x4E, 0xF, 0xF, true);
    return __builtin_bit_cast(float, a);
}

// ---------------------------------------------------------------------------
// MFMA GEMM: C[M,N] = A[M,K] @ W[N,K]^T + bias.  (validated in round 1)
// ---------------------------------------------------------------------------
template<typename AT, typename CT>
__global__ __launch_bounds__(256, 2)
void gemm_mfma(const AT* __restrict__ A, const float* __restrict__ W,
               const float* __restrict__ bias, CT* __restrict__ Cout,
               int M, int N, int K)
{
    __shared__ alignas(16) u32 As32[128 * 32];   // [row][8 slots of 16B], swizzled
    __shared__ alignas(16) u32 Bs32[64 * 32];

    const int tid  = threadIdx.x;
    const int lane = tid & 63;
    const int wave = tid >> 6;        // 0..3
    const int wm   = wave >> 1;       // 0..1 -> m offset 64*wm
    const int wn   = wave & 1;        // 0..1 -> n offset 32*wn
    const int m0   = blockIdx.y * 128;
    const int n0   = blockIdx.x * 64;
    const int lr   = lane & 15;       // fragment row/col
    const int lg   = lane >> 4;       // k-group 0..3

    floatx4 acc[4][2] = {};

    for (int kc = 0; kc < K; kc += 64) {
        // ---- stage A: 128 rows x 64 f16 = 1024 x 16B slots, 4 iters ----
        #pragma unroll
        for (int it = 0; it < 4; ++it) {
            const int s    = it * 256 + tid;
            const int row  = s >> 3;          // 0..127
            const int slot = s & 7;           // 0..7 (8 f16 each)
            const AT* src  = A + (size_t)(m0 + row) * K + kc + slot * 8;
            half8_t v;
            if constexpr (sizeof(AT) == 2) {
                v = *reinterpret_cast<const half8_t*>(src);
            } else {
                const float4* s4 = reinterpret_cast<const float4*>(src);
                float4 lo = s4[0], hi = s4[1];
                v[0] = (_Float16)lo.x; v[1] = (_Float16)lo.y;
                v[2] = (_Float16)lo.z; v[3] = (_Float16)lo.w;
                v[4] = (_Float16)hi.x; v[5] = (_Float16)hi.y;
                v[6] = (_Float16)hi.z; v[7] = (_Float16)hi.w;
            }
            const int sw = slot ^ (row & 7);
            *reinterpret_cast<half8_t*>(&As32[row * 32 + sw * 4]) = v;
        }
        // ---- stage B: 64 rows x 64 f16 = 512 slots, 2 iters (fp32 W) ----
        #pragma unroll
        for (int it = 0; it < 2; ++it) {
            const int s    = it * 256 + tid;
            const int row  = s >> 3;          // 0..63
            const int slot = s & 7;
            const float* src = W + (size_t)(n0 + row) * K + kc + slot * 8;
            const float4* s4 = reinterpret_cast<const float4*>(src);
            float4 lo = s4[0], hi = s4[1];
            half8_t v;
            v[0] = (_Float16)lo.x; v[1] = (_Float16)lo.y;
            v[2] = (_Float16)lo.z; v[3] = (_Float16)lo.w;
            v[4] = (_Float16)hi.x; v[5] = (_Float16)hi.y;
            v[6] = (_Float16)hi.z; v[7] = (_Float16)hi.w;
            const int sw = slot ^ (row & 7);
            *reinterpret_cast<half8_t*>(&Bs32[row * 32 + sw * 4]) = v;
        }
        __syncthreads();

        #pragma unroll
        for (int ks = 0; ks < 2; ++ks) {
            half8_t af[4], bf[2];
            #pragma unroll
            for (int fm = 0; fm < 4; ++fm) {
                const int row  = wm * 64 + fm * 16 + lr;
                const int slot = ks * 4 + lg;
                const int sw   = slot ^ (row & 7);
                af[fm] = *reinterpret_cast<const half8_t*>(&As32[row * 32 + sw * 4]);
            }
            #pragma unroll
            for (int fn = 0; fn < 2; ++fn) {
                const int row  = wn * 32 + fn * 16 + lr;
                const int slot = ks * 4 + lg;
                const int sw   = slot ^ (row & 7);
                bf[fn] = *reinterpret_cast<const half8_t*>(&Bs32[row * 32 + sw * 4]);
            }
            #pragma unroll
            for (int fm = 0; fm < 4; ++fm)
                #pragma unroll
                for (int fn = 0; fn < 2; ++fn)
                    acc[fm][fn] = __builtin_amdgcn_mfma_f32_16x16x32_f16(
                        af[fm], bf[fn], acc[fm][fn], 0, 0, 0);
        }
        __syncthreads();
    }

    // ---- epilogue: D[row=(lane>>4)*4+reg][col=lane&15] + bias ----
    #pragma unroll
    for (int fn = 0; fn < 2; ++fn) {
        const int n = n0 + wn * 32 + fn * 16 + lr;
        const float bv = bias[n];
        #pragma unroll
        for (int fm = 0; fm < 4; ++fm) {
            #pragma unroll
            for (int r = 0; r < 4; ++r) {
                const int m = m0 + wm * 64 + fm * 16 + lg * 4 + r;
                Cout[(size_t)m * N + n] = (CT)(acc[fm][fn][r] + bv);
            }
        }
    }
}

// ---------------------------------------------------------------------------
// Persistent GRU scan, v4: VALU dot2 with PINNED register allocation.
// One WG per batch, 512 threads = 8 waves = exactly 2 waves/SIMD.
// amdgpu_waves_per_eu(2,2) caps occupancy at 2 -> 256-VGPR budget, so the
// 192 weight half2s stay in ARCH VGPRs (v1/v2's failure: compiler chose
// 128/64 VGPRs + AGPR banking -> one v_accvgpr_read per dot2, 2x hot loop).
// Thread t: row j = t>>1, k-half kh = t&1 (128 k-values, 64 half2/gate).
// VALU dot work per step per SIMD: 2 waves x 192 insts x 2cy = 768 cy floor.
// h double-buffered in LDS (ONE barrier/step, v3-validated), 2-way read
// aliasing only (free per m136). DPP pair-reduce for the k-halves, DPP xor2
// for output pairing (no LDS-pipe shfl). gx prefetched a FULL step ahead
// (~1100cy slack > ~900cy HBM latency); final-step overrun lands in hbuf
// (valid workspace). Fast exp/rcp gates (numerics validated since v2).
// ---------------------------------------------------------------------------
__global__ __attribute__((amdgpu_flat_work_group_size(512, 512),
                          amdgpu_waves_per_eu(2, 2)))
void gru_scan(const _Float16* __restrict__ gx,   // [B, T, 768] incl. b_ih
              const float* __restrict__ Whh,     // [768, 256]
              const float* __restrict__ bhh,     // [768]
              _Float16* __restrict__ hout)       // [B, T, 256]
{
    const int b  = blockIdx.x;
    const int t  = threadIdx.x;
    const int j  = t >> 1;          // 0..255
    const int kh = t & 1;           // k-half

    // ---- weights: rows {j, 256+j, 512+j}, this thread's 128-k half ----
    half2_t w0[64], w1[64], w2[64];
    {
        const float2* q0 = reinterpret_cast<const float2*>(Whh + (size_t)j * HH + kh * 128);
        const float2* q1 = q0 + 128 * HH;    // +256 rows (float2 units: 256*HH/2)
        const float2* q2 = q0 + 256 * HH;    // +512 rows
        #pragma unroll
        for (int i = 0; i < 64; ++i) {
            const float2 a = q0[i], c = q1[i], d = q2[i];
            w0[i] = half2_t{(_Float16)a.x, (_Float16)a.y};
            w1[i] = half2_t{(_Float16)c.x, (_Float16)c.y};
            w2[i] = half2_t{(_Float16)d.x, (_Float16)d.y};
        }
    }
    const float bh_r = bhh[j], bh_z = bhh[HH + j], bh_n = bhh[2*HH + j];

    __shared__ alignas(16) _Float16 Hs[2][HH];   // double-buffered h (2x512B)
    reinterpret_cast<_Float16*>(Hs)[t] = (_Float16)0.f;   // zero both buffers
    float hprev = 0.f;

    const _Float16* gp = gx + (size_t)b * TT * G3 + j;
    u32* opw = (u32*)(hout + (size_t)b * TT * HH);

    // step-0 input gates
    _Float16 pxr = gp[0], pxz = gp[HH], pxn = gp[2*HH];
    __syncthreads();

    for (int step = 0; step < TT; ++step) {
        // prefetch NEXT step's gx now (full-step slack covers HBM latency)
        const _Float16 nxr = gp[G3];
        const _Float16 nxz = gp[G3 + HH];
        const _Float16 nxn = gp[G3 + 2*HH];

        // ---- 16 x ds_read_b128 over this thread's 128-value k-half ----
        const uint4* hb = reinterpret_cast<const uint4*>(Hs[step & 1] + kh * 128);
        float ar = 0.f, az = 0.f, an = 0.f;
        #pragma unroll
        for (int c = 0; c < 16; ++c) {
            const uint4 hv = hb[c];
            const half2_t ha = bch2(hv.x), hc = bch2(hv.y);
            const half2_t hd = bch2(hv.z), he = bch2(hv.w);
            ar = dot2f(ha, w0[4*c+0], ar); az = dot2f(ha, w1[4*c+0], az); an = dot2f(ha, w2[4*c+0], an);
            ar = dot2f(hc, w0[4*c+1], ar); az = dot2f(hc, w1[4*c+1], az); an = dot2f(hc, w2[4*c+1], an);
            ar = dot2f(hd, w0[4*c+2], ar); az = dot2f(hd, w1[4*c+2], az); an = dot2f(hd, w2[4*c+2], an);
            ar = dot2f(he, w0[4*c+3], ar); az = dot2f(he, w1[4*c+3], az); an = dot2f(he, w2[4*c+3], an);
        }
        // combine k-halves: lanes t,t^1 (same j) both end with the full sum
        ar = pair_sum(ar);
        az = pair_sum(az);
        an = pair_sum(an);

        const float r = fast_rcp(1.f + __expf(-((float)pxr + ar + bh_r)));
        const float z = fast_rcp(1.f + __expf(-((float)pxz + az + bh_z)));
        const float e = __expf(2.f * ((float)pxn + r * (an + bh_n)));
        const float n = 1.f - 2.f * fast_rcp(e + 1.f);
        const float hnew = (1.f - z) * n + z * hprev;
        hprev = hnew;

        // pack pair {h[j], h[j+1]} on lanes t%4==0 (j even, kh 0)
        const float hoth = dpp_xor2(hnew);     // row j^1's value
        if ((t & 3) == 0) {
            const half2_t hp{(_Float16)hnew, (_Float16)hoth};
            const u32 pu = __builtin_bit_cast(u32, hp);
            reinterpret_cast<u32*>(Hs[(step + 1) & 1])[t >> 2] = pu;  // next buffer
            opw[t >> 2] = pu;                                          // layer output
        }
        __syncthreads();   // next-buffer writes visible; current-buffer reads done

        gp += G3; opw += HH/2;
        pxr = nxr; pxz = nxz; pxn = nxn;
    }
}

// ---------------------------------------------------------------------------
extern "C" void kernel_launch(void* const* d_in, const int* in_sizes, int n_in,
                              void* d_out, int out_size, void* d_ws, size_t ws_size,
                              hipStream_t stream) {
    const float* x    = (const float*)d_in[0];
    const float* Wih0 = (const float*)d_in[1];
    const float* Whh0 = (const float*)d_in[2];
    const float* bih0 = (const float*)d_in[3];
    const float* bhh0 = (const float*)d_in[4];
    const float* Wih1 = (const float*)d_in[5];
    const float* Whh1 = (const float*)d_in[6];
    const float* bih1 = (const float*)d_in[7];
    const float* bhh1 = (const float*)d_in[8];
    const float* fcw  = (const float*)d_in[9];
    const float* fcb  = (const float*)d_in[10];
    float* out = (float*)d_out;

    // workspace: gx buffer (201 MB, reused for both layers) + h buffer (64 MB)
    _Float16* gxbuf = (_Float16*)d_ws;
    _Float16* hbuf  = (_Float16*)((char*)d_ws + (size_t)MTOT * G3 * sizeof(_Float16));

    const dim3 blk(256);
    // 1) gx0 = x @ W_ih0^T + b_ih0
    gemm_mfma<float, _Float16><<<dim3(G3/64, MTOT/128), blk, 0, stream>>>(
        x, Wih0, bih0, gxbuf, MTOT, G3, II);
    // 2) scan layer 0 -> h0
    gru_scan<<<dim3(BB), dim3(512), 0, stream>>>(gxbuf, Whh0, bhh0, hbuf);
    // 3) gx1 = h0 @ W_ih1^T + b_ih1 (overwrites gx buffer)
    gemm_mfma<_Float16, _Float16><<<dim3(G3/64, MTOT/128), blk, 0, stream>>>(
        hbuf, Wih1, bih1, gxbuf, MTOT, G3, HH);
    // 4) scan layer 1 -> h1 (overwrites h buffer)
    gru_scan<<<dim3(BB), dim3(512), 0, stream>>>(gxbuf, Whh1, bhh1, hbuf);
    // 5) out = h1 @ fc_w^T + fc_b
    gemm_mfma<_Float16, float><<<dim3(CC/64, MTOT/128), blk, 0, stream>>>(
        hbuf, fcw, fcb, out, MTOT, CC, HH);
}